// Round 3
// baseline (756.190 us; speedup 1.0000x reference)
//
#include <hip/hip_runtime.h>
#include <cstddef>
#include <cstdint>

#define B_ 8192
#define S_ 14
#define K_ 512
#define D_ 256

typedef __attribute__((ext_vector_type(8))) short bfx8;
typedef __attribute__((ext_vector_type(4))) float fx4;

typedef __attribute__((address_space(3))) unsigned int       lds_u32;
typedef const __attribute__((address_space(1))) unsigned int glb_u32;

__device__ __forceinline__ void gload16(const void* g, void* l) {
    __builtin_amdgcn_global_load_lds((glb_u32*)g, (lds_u32*)l, 16, 0, 0);
}

// RNE float -> bf16 bits
__device__ __forceinline__ unsigned short f2bf(float x) {
    union { float f; unsigned int u; } v; v.f = x;
    unsigned int r = (v.u + 0x7FFFu + ((v.u >> 16) & 1u)) >> 16;
    return (unsigned short)r;
}
__device__ __forceinline__ float bf2f(unsigned short h) {
    union { unsigned int u; float f; } v; v.u = ((unsigned int)h) << 16;
    return v.f;
}

// ---------------------------------------------------------------------------
// per-row inverse L2 norm (1 wave per row of D=256 floats)
// ---------------------------------------------------------------------------
__global__ __launch_bounds__(64) void rownorm_kernel(
    const float* __restrict__ rows, float* __restrict__ invn)
{
    const int row  = blockIdx.x;
    const int lane = threadIdx.x;
    const float4 v = *reinterpret_cast<const float4*>(rows + (size_t)row * D_ + lane * 4);
    float ss = v.x * v.x + v.y * v.y + v.z * v.z + v.w * v.w;
    #pragma unroll
    for (int m = 32; m >= 1; m >>= 1) ss += __shfl_xor(ss, m, 64);
    if (lane == 0) invn[row] = 1.0f / fmaxf(sqrtf(ss), 1e-12f);
}

// ---------------------------------------------------------------------------
// 3-way bf16 split of key (B,S,D) fp32 -> planes in (S,B,D) layout
// ---------------------------------------------------------------------------
__global__ __launch_bounds__(256) void split_key_kernel(
    const float* __restrict__ key,
    unsigned short* __restrict__ ph, unsigned short* __restrict__ pm,
    unsigned short* __restrict__ pl)
{
    const int gid  = blockIdx.x * 256 + threadIdx.x;
    const int e    = gid * 4;                 // flat elem in key natural order
    const int b    = e / (S_ * D_);
    const int rem  = e - b * (S_ * D_);
    const int s    = rem >> 8;                // D_=256
    const int d    = rem & 255;
    const float4 x = *reinterpret_cast<const float4*>(key + e);
    const size_t o = ((size_t)s * B_ + b) * D_ + d;

    float xs[4] = { x.x, x.y, x.z, x.w };
    unsigned short hh[4], mm[4], ll[4];
    #pragma unroll
    for (int i = 0; i < 4; ++i) {
        unsigned short a = f2bf(xs[i]);
        float r1 = xs[i] - bf2f(a);
        unsigned short bq = f2bf(r1);
        float r2 = r1 - bf2f(bq);
        unsigned short c = f2bf(r2);
        hh[i] = a; mm[i] = bq; ll[i] = c;
    }
    *reinterpret_cast<ushort4*>(ph + o) = make_ushort4(hh[0], hh[1], hh[2], hh[3]);
    *reinterpret_cast<ushort4*>(pm + o) = make_ushort4(mm[0], mm[1], mm[2], mm[3]);
    *reinterpret_cast<ushort4*>(pl + o) = make_ushort4(ll[0], ll[1], ll[2], ll[3]);
}

// ---------------------------------------------------------------------------
// 3-way bf16 split of a (S,K,D) fp32 tensor -> same-layout planes
// ---------------------------------------------------------------------------
__global__ __launch_bounds__(256) void split_mem_kernel(
    const float* __restrict__ mem,
    unsigned short* __restrict__ ph, unsigned short* __restrict__ pm,
    unsigned short* __restrict__ pl)
{
    const int e    = (blockIdx.x * 256 + threadIdx.x) * 4;
    const float4 x = *reinterpret_cast<const float4*>(mem + e);
    float xs[4] = { x.x, x.y, x.z, x.w };
    unsigned short hh[4], mm[4], ll[4];
    #pragma unroll
    for (int i = 0; i < 4; ++i) {
        unsigned short a = f2bf(xs[i]);
        float r1 = xs[i] - bf2f(a);
        unsigned short bq = f2bf(r1);
        float r2 = r1 - bf2f(bq);
        unsigned short c = f2bf(r2);
        hh[i] = a; mm[i] = bq; ll[i] = c;
    }
    *reinterpret_cast<ushort4*>(ph + e) = make_ushort4(hh[0], hh[1], hh[2], hh[3]);
    *reinterpret_cast<ushort4*>(pm + e) = make_ushort4(mm[0], mm[1], mm[2], mm[3]);
    *reinterpret_cast<ushort4*>(pl + e) = make_ushort4(ll[0], ll[1], ll[2], ll[3]);
}

// ---------------------------------------------------------------------------
// MFMA score GEMM + per-block argmax partials.
// 256 thr = 4 waves (2x2), tile 128(b) x 128(k), 51.7KB LDS -> 3 blocks/CU.
// Round-3 change: drain-covered pipeline within a SINGLE LDS buffer.
// Per dc-step:  read ALL 24 fragments (A+B) to regs -> barrier (lgkm-only)
//               -> issue stage(dc+1) (12 gloads in flight)
//               -> 96 MFMA (~466 cyc) cover the load latency
//               -> barrier (vmcnt(0) drain, now mostly hidden).
// Pair order and per-acc MFMA issue order are UNCHANGED from the verified
// kernel -> scores bitwise identical.  Regs: 64 acc + 96 frag ~ 168;
// __launch_bounds__(256,3) keeps 3 waves/SIMD to match LDS' 3 blocks/CU.
// XOR-swizzled staging/reads.  Bijective XCD swizzle; k-block fastest.
// ---------------------------------------------------------------------------
__global__ __launch_bounds__(256, 3) void gemm_argmax_kernel(
    const unsigned short* __restrict__ kh, const unsigned short* __restrict__ km,
    const unsigned short* __restrict__ kl,
    const unsigned short* __restrict__ mh, const unsigned short* __restrict__ mm_,
    const unsigned short* __restrict__ ml,
    const float* __restrict__ invn,
    float* __restrict__ pV, int* __restrict__ pI)
{
    __shared__ short T[6][128 * 32];   // 0..2 = key h/m/l, 3..5 = mem h/m/l
    __shared__ float sInv[128];
    __shared__ float bV[128][2];
    __shared__ int   bI[128][2];

    // bijective XCD swizzle (nwg = 3584 = 8*448)
    const int orig = blockIdx.x;
    const int wg   = (orig & 7) * 448 + (orig >> 3);
    const int by   = wg & 3;          // k-block (fastest: key-tile sharers adjacent)
    const int bx   = (wg >> 2) & 63;  // b-block
    const int s    = wg >> 8;

    const int t    = threadIdx.x;
    const int b0   = bx * 128;
    const int n0   = by * 128;
    const int w    = t >> 6;
    const int lane = t & 63;
    const int wm   = w >> 1, wn = w & 1;
    const int lr   = lane & 15, lg = lane >> 4;

    const size_t sB = (size_t)s * B_;
    const size_t sK = (size_t)s * K_;

    const unsigned short* __restrict__ APl[3] = { kh, km, kl };
    const unsigned short* __restrict__ BPl[3] = { mh, mm_, ml };

    fx4 acc[4][4];
    #pragma unroll
    for (int i = 0; i < 4; ++i)
        #pragma unroll
        for (int j = 0; j < 4; ++j) acc[i][j] = (fx4)0.0f;

    // staging: lane covers (row = l>>2, phys chunk = l&3);
    // pre-swizzled source chunk = (l&3) ^ ((l>>3)&3)
    const int rsub = lane >> 2;
    const int csw  = (((lane & 3) ^ ((lane >> 3) & 3)) * 8);
    // read-side: phys chunk = lg ^ ((row>>1)&3)
    const int rdof = ((lg ^ ((lr >> 1) & 3)) * 8);

    auto stage = [&](int dcv) {
        const int dco = dcv * 32 + csw;
        #pragma unroll
        for (int p = 0; p < 3; ++p) {
            #pragma unroll
            for (int u = 0; u < 2; ++u) {
                const int R0 = w * 32 + u * 16;
                gload16(APl[p] + (sB + b0 + R0 + rsub) * D_ + dco, &T[p][R0 * 32]);
                gload16(BPl[p] + (sK + n0 + R0 + rsub) * D_ + dco, &T[3 + p][R0 * 32]);
            }
        }
    };

    stage(0);
    __syncthreads();   // tiles for dc=0 resident

    for (int dc = 0; dc < 8; ++dc) {
        // ---- read ALL fragments of this dc-step into registers (24 b128) ----
        bfx8 bf[3][4];
        #pragma unroll
        for (int bp = 0; bp < 3; ++bp)
            #pragma unroll
            for (int j = 0; j < 4; ++j)
                bf[bp][j] = *reinterpret_cast<const bfx8*>(
                    &T[3 + bp][(wn * 64 + j * 16 + lr) * 32 + rdof]);
        bfx8 af[3][4];
        #pragma unroll
        for (int ap = 0; ap < 3; ++ap)
            #pragma unroll
            for (int i = 0; i < 4; ++i)
                af[ap][i] = *reinterpret_cast<const bfx8*>(
                    &T[ap][(wm * 64 + i * 16 + lr) * 32 + rdof]);

        __syncthreads();   // all waves done reading LDS (lgkm-only; no vmem pending)

        if (dc < 7) stage(dc + 1);   // 12 gloads in flight, land under MFMA

        // ---- compute 6 term-pairs from registers (pair order unchanged) ----
        #pragma unroll
        for (int ap = 0; ap < 3; ++ap) {
            #pragma unroll
            for (int bp = 0; bp < 3 - ap; ++bp) {
                __builtin_amdgcn_s_setprio(1);
                #pragma unroll
                for (int i = 0; i < 4; ++i)
                    #pragma unroll
                    for (int j = 0; j < 4; ++j)
                        acc[i][j] = __builtin_amdgcn_mfma_f32_16x16x32_bf16(
                            af[ap][i], bf[bp][j], acc[i][j], 0, 0, 0);
                __builtin_amdgcn_s_setprio(0);
            }
        }
        __syncthreads();   // vmcnt(0) drain of prefetch -- covered by MFMA above
    }

    if (t < 128) sInv[t] = invn[sK + n0 + t];
    __syncthreads();

    #pragma unroll
    for (int i = 0; i < 4; ++i) {
        #pragma unroll
        for (int r = 0; r < 4; ++r) {
            float bv = -3.4e38f; int bi = 0x7fffffff;
            #pragma unroll
            for (int j = 0; j < 4; ++j) {
                const int kloc = wn * 64 + j * 16 + lr;
                const float v  = acc[i][j][r] * sInv[kloc];
                const int  kg  = n0 + kloc;
                if (v > bv || (v == bv && kg < bi)) { bv = v; bi = kg; }
            }
            #pragma unroll
            for (int msk = 1; msk < 16; msk <<= 1) {
                const float ov = __shfl_xor(bv, msk, 64);
                const int   oi = __shfl_xor(bi, msk, 64);
                if (ov > bv || (ov == bv && oi < bi)) { bv = ov; bi = oi; }
            }
            if (lr == 0) {
                const int mrow = wm * 64 + i * 16 + lg * 4 + r;
                bV[mrow][wn] = bv; bI[mrow][wn] = bi;
            }
        }
    }
    __syncthreads();

    if (t < 128) {
        const float v0 = bV[t][0], v1 = bV[t][1];
        const int   i0 = bI[t][0], i1 = bI[t][1];
        const bool take1 = (v1 > v0) || (v1 == v0 && i1 < i0);
        const size_t o = ((size_t)s * 4 + by) * B_ + b0 + t;
        pV[o] = take1 ? v1 : v0;
        pI[o] = take1 ? i1 : i0;
    }
}

// ---------------------------------------------------------------------------
// combine 4 n-block partials -> ind1[s*B+b]
// ---------------------------------------------------------------------------
__global__ __launch_bounds__(256) void combine1_kernel(
    const float* __restrict__ pV, const int* __restrict__ pI,
    int* __restrict__ ind1)
{
    const int idx = blockIdx.x * 256 + threadIdx.x;   // s*B + b
    const int s   = idx >> 13;                        // B_=8192
    const int b   = idx & 8191;
    float bv = -3.4e38f; int bi = 0x7fffffff;
    #pragma unroll
    for (int nb = 0; nb < 4; ++nb) {
        const size_t o = ((size_t)s * 4 + nb) * B_ + b;
        const float v = pV[o]; const int i = pI[o];
        if (v > bv || (v == bv && i < bi)) { bv = v; bi = i; }
    }
    ind1[idx] = bi;
}

// ---------------------------------------------------------------------------
// combine partials -> ind2, gather output row
// ---------------------------------------------------------------------------
__global__ __launch_bounds__(256) void combine2_out_kernel(
    const float* __restrict__ pV, const int* __restrict__ pI,
    const float* __restrict__ value, const float* __restrict__ newmem,
    float* __restrict__ out)
{
    const int row  = blockIdx.x * 4 + (threadIdx.x >> 6);  // s*B + b
    const int lane = threadIdx.x & 63;
    const int s    = row >> 13;
    const int b    = row & 8191;
    float bv = -3.4e38f; int bi = 0x7fffffff;
    #pragma unroll
    for (int nb = 0; nb < 4; ++nb) {
        const size_t o = ((size_t)s * 4 + nb) * B_ + b;
        const float v = pV[o]; const int i = pI[o];
        if (v > bv || (v == bv && i < bi)) { bv = v; bi = i; }
    }
    const float4 vv = *reinterpret_cast<const float4*>(
        value + (size_t)b * (S_ * D_) + lane * 4);          // value[b][0][:]
    const float4 mmv = *reinterpret_cast<const float4*>(
        newmem + ((size_t)s * K_ + bi) * D_ + lane * 4);
    float4 o4;
    o4.x = vv.x + mmv.x; o4.y = vv.y + mmv.y;
    o4.z = vv.z + mmv.z; o4.w = vv.w + mmv.w;
    *reinterpret_cast<float4*>(out + ((size_t)b * S_ + s) * D_ + lane * 4) = o4;
}

// ---------------------------------------------------------------------------
// update chain: deterministic chunked counting sort + gather-EMA
// ---------------------------------------------------------------------------
__global__ __launch_bounds__(256) void u1_hist_kernel(
    const int* __restrict__ ind1, int* __restrict__ hist)
{
    __shared__ int h[K_];
    const int t = threadIdx.x, c = blockIdx.x, s = blockIdx.y;
    h[t] = 0; h[t + 256] = 0;
    __syncthreads();
    const int k = ind1[(size_t)s * B_ + c * 256 + t];
    atomicAdd(&h[k], 1);
    __syncthreads();
    hist[((size_t)s * 32 + c) * K_ + t]       = h[t];
    hist[((size_t)s * 32 + c) * K_ + t + 256] = h[t + 256];
}

__global__ __launch_bounds__(512) void u2_scan_kernel(
    int* __restrict__ hist, int* __restrict__ cnt, int* __restrict__ offs)
{
    __shared__ int sc[K_];
    const int k = threadIdx.x, s = blockIdx.x;
    int run = 0;
    for (int c = 0; c < 32; ++c) {
        const size_t o = ((size_t)s * 32 + c) * K_ + k;
        const int x = hist[o];
        hist[o] = run;           // exclusive per-chunk base within slot
        run += x;
    }
    cnt[s * K_ + k] = run;
    sc[k] = run;
    __syncthreads();
    for (int off = 1; off < K_; off <<= 1) {
        int v = (k >= off) ? sc[k - off] : 0;
        __syncthreads();
        sc[k] += v;
        __syncthreads();
    }
    offs[s * K_ + k] = sc[k] - run;   // exclusive slot base
}

__global__ __launch_bounds__(256) void u3_scatter_kernel(
    const int* __restrict__ ind1, const int* __restrict__ hist,
    const int* __restrict__ offs, int* __restrict__ csr)
{
    __shared__ int sk[256];
    const int t = threadIdx.x, c = blockIdx.x, s = blockIdx.y;
    const int b = c * 256 + t;
    const int k = ind1[(size_t)s * B_ + b];
    sk[t] = k;
    __syncthreads();
    int rank = 0;
    for (int j = 0; j < t; ++j) rank += (sk[j] == k);
    const int pos = offs[s * K_ + k] + hist[((size_t)s * 32 + c) * K_ + k] + rank;
    csr[(size_t)s * B_ + pos] = b;
}

__global__ __launch_bounds__(64) void u4_gather_kernel(
    const int* __restrict__ csr, const int* __restrict__ cnt,
    const int* __restrict__ offs, const float* __restrict__ value,
    const float* __restrict__ memory, float* __restrict__ newmem)
{
    const int k = blockIdx.x, s = blockIdx.y, lane = threadIdx.x;
    const int n = cnt[s * K_ + k];
    const int base = offs[s * K_ + k];
    float4 a; a.x = a.y = a.z = a.w = 0.0f;
    for (int i = 0; i < n; ++i) {
        const int b = csr[(size_t)s * B_ + base + i];
        const float4 v = *reinterpret_cast<const float4*>(
            value + ((size_t)b * S_ + s) * D_ + lane * 4);
        a.x += v.x; a.y += v.y; a.z += v.z; a.w += v.w;
    }
    const float inv = 1.0f / ((float)n + 1e-6f);
    const size_t o = ((size_t)s * K_ + k) * D_ + lane * 4;
    const float4 mo = *reinterpret_cast<const float4*>(memory + o);
    float4 r;
    r.x = mo.x * 0.999f + a.x * inv * 0.001f;
    r.y = mo.y * 0.999f + a.y * inv * 0.001f;
    r.z = mo.z * 0.999f + a.z * inv * 0.001f;
    r.w = mo.w * 0.999f + a.w * inv * 0.001f;
    *reinterpret_cast<float4*>(newmem + o) = r;
}

// ===========================================================================
// FALLBACK (round-1 verified fp32 path; used if ws too small)
// ===========================================================================
template <int MODE>
__global__ __launch_bounds__(256) void score_argmax_kernel(
    const float* __restrict__ key, const float* __restrict__ mem,
    const float* __restrict__ invn, const float* __restrict__ value,
    float* __restrict__ out, int* __restrict__ ind_out)
{
    __shared__ __align__(16) float kt[64][36];
    __shared__ __align__(16) float mt[64][36];
    __shared__ float redV[64][16];
    __shared__ int   redI[64][16];

    const int t  = threadIdx.x;
    const int s  = blockIdx.y;
    const int b0 = blockIdx.x * 64;
    const int tb = t & 15;
    const int tk = t >> 4;

    float best[4]; int bidx[4];
    #pragma unroll
    for (int i = 0; i < 4; ++i) { best[i] = -3.4e38f; bidx[i] = 0; }

    for (int kc = 0; kc < 8; ++kc) {
        float acc[4][4];
        #pragma unroll
        for (int i = 0; i < 4; ++i)
            #pragma unroll
            for (int j = 0; j < 4; ++j) acc[i][j] = 0.0f;

        for (int dc = 0; dc < 8; ++dc) {
            #pragma unroll
            for (int u = 0; u < 2; ++u) {
                const int f = t + u * 256;
                const int row = f >> 3;
                const int c4 = f & 7;
                *reinterpret_cast<float4*>(&kt[row][c4 * 4]) =
                    *reinterpret_cast<const float4*>(
                        key + (((size_t)(b0 + row)) * S_ + s) * D_ + dc * 32 + c4 * 4);
                *reinterpret_cast<float4*>(&mt[row][c4 * 4]) =
                    *reinterpret_cast<const float4*>(
                        mem + (((size_t)s * K_) + kc * 64 + row) * D_ + dc * 32 + c4 * 4);
            }
            __syncthreads();
            #pragma unroll
            for (int d4 = 0; d4 < 8; ++d4) {
                float4 a[4], b[4];
                #pragma unroll
                for (int i = 0; i < 4; ++i)
                    a[i] = *reinterpret_cast<const float4*>(&kt[tb + i * 16][d4 * 4]);
                #pragma unroll
                for (int j = 0; j < 4; ++j)
                    b[j] = *reinterpret_cast<const float4*>(&mt[tk + j * 16][d4 * 4]);
                #pragma unroll
                for (int i = 0; i < 4; ++i)
                    #pragma unroll
                    for (int j = 0; j < 4; ++j)
                        acc[i][j] += a[i].x * b[j].x + a[i].y * b[j].y +
                                     a[i].z * b[j].z + a[i].w * b[j].w;
            }
            __syncthreads();
        }
        #pragma unroll
        for (int j = 0; j < 4; ++j) {
            const int kabs = kc * 64 + tk + j * 16;
            const float inv = invn[s * K_ + kabs];
            #pragma unroll
            for (int i = 0; i < 4; ++i) {
                const float v = acc[i][j] * inv;
                if (v > best[i] || (v == best[i] && kabs < bidx[i])) {
                    best[i] = v; bidx[i] = kabs;
                }
            }
        }
    }
    #pragma unroll
    for (int i = 0; i < 4; ++i) {
        redV[tb + i * 16][tk] = best[i];
        redI[tb + i * 16][tk] = bidx[i];
    }
    __syncthreads();
    if (t < 64) {
        float bv = redV[t][0]; int bi = redI[t][0];
        #pragma unroll
        for (int g = 1; g < 16; ++g) {
            const float v = redV[t][g]; const int ix = redI[t][g];
            if (v > bv || (v == bv && ix < bi)) { bv = v; bi = ix; }
        }
        if (MODE == 0) ind_out[(size_t)s * B_ + b0 + t] = bi;
        else           redI[t][0] = bi;
    }
    if (MODE == 1) {
        __syncthreads();
        const int w = t >> 6, lane = t & 63;
        for (int r = w; r < 64; r += 4) {
            const int bg = b0 + r;
            const int kk = redI[r][0];
            const float4 vv = *reinterpret_cast<const float4*>(
                value + (size_t)bg * (S_ * D_) + lane * 4);
            const float4 mmv = *reinterpret_cast<const float4*>(
                mem + ((size_t)s * K_ + kk) * D_ + lane * 4);
            float4 o;
            o.x = vv.x + mmv.x; o.y = vv.y + mmv.y;
            o.z = vv.z + mmv.z; o.w = vv.w + mmv.w;
            *reinterpret_cast<float4*>(
                out + (((size_t)bg) * S_ + s) * D_ + lane * 4) = o;
        }
    }
}

__global__ __launch_bounds__(256) void update_kernel(
    const int* __restrict__ ind1, const float* __restrict__ value,
    const float* __restrict__ memory, float* __restrict__ newmem)
{
    const int k0 = blockIdx.x * 4, s = blockIdx.y, t = threadIdx.x;
    __shared__ int sIdx[256];
    float a0 = 0.f, a1 = 0.f, a2 = 0.f, a3 = 0.f;
    int c0 = 0, c1 = 0, c2 = 0, c3 = 0;
    for (int b0 = 0; b0 < B_; b0 += 256) {
        sIdx[t] = ind1[(size_t)s * B_ + b0 + t];
        __syncthreads();
        for (int bb = 0; bb < 256; ++bb) {
            const int ix = sIdx[bb];
            const unsigned r = (unsigned)(ix - k0);
            if (r < 4u) {
                const float v = value[(((size_t)(b0 + bb)) * S_ + s) * D_ + t];
                if      (r == 0u) { a0 += v; ++c0; }
                else if (r == 1u) { a1 += v; ++c1; }
                else if (r == 2u) { a2 += v; ++c2; }
                else              { a3 += v; ++c3; }
            }
        }
        __syncthreads();
    }
    const float accs[4] = { a0, a1, a2, a3 };
    const int   cns [4] = { c0, c1, c2, c3 };
    #pragma unroll
    for (int kk = 0; kk < 4; ++kk) {
        const size_t off = ((size_t)s * K_ + k0 + kk) * D_ + t;
        const float mean = accs[kk] / ((float)cns[kk] + 1e-6f);
        newmem[off] = memory[off] * 0.999f + mean * 0.001f;
    }
}

// ---------------------------------------------------------------------------
extern "C" void kernel_launch(void* const* d_in, const int* in_sizes, int n_in,
                              void* d_out, int out_size, void* d_ws, size_t ws_size,
                              hipStream_t stream)
{
    const float* key    = (const float*)d_in[0];
    const float* value  = (const float*)d_in[1];
    const float* memory = (const float*)d_in[2];

    float* out    = (float*)d_out;                       // (B,S,D)
    float* newmem = out + (size_t)B_ * S_ * D_;          // (S,K,D)

    // ---- workspace layout for the MFMA path ----
    const size_t keyPlane = (size_t)S_ * B_ * D_;        // elems (bf16)
    const size_t memPlane = (size_t)S_ * K_ * D_;
    char* p = (char*)d_ws;
    size_t need = 0;
    auto alloc = [&](size_t bytes) -> char* {
        char* r = p + need;
        need += (bytes + 255) & ~(size_t)255;
        return r;
    };
    unsigned short* kh  = (unsigned short*)alloc(keyPlane * 2);
    unsigned short* km  = (unsigned short*)alloc(keyPlane * 2);
    unsigned short* kl  = (unsigned short*)alloc(keyPlane * 2);
    unsigned short* mh  = (unsigned short*)alloc(memPlane * 2);
    unsigned short* mm  = (unsigned short*)alloc(memPlane * 2);
    unsigned short* ml  = (unsigned short*)alloc(memPlane * 2);
    float* invn   = (float*)alloc((size_t)S_ * K_ * 4);
    float* pV     = (float*)alloc((size_t)S_ * 4 * B_ * 4);
    int*   pI     = (int*)  alloc((size_t)S_ * 4 * B_ * 4);
    int*   ind1   = (int*)  alloc((size_t)S_ * B_ * 4);
    int*   hist   = (int*)  alloc((size_t)S_ * 32 * K_ * 4);
    int*   cnt    = (int*)  alloc((size_t)S_ * K_ * 4);
    int*   offs   = (int*)  alloc((size_t)S_ * K_ * 4);
    int*   csr    = (int*)  alloc((size_t)S_ * B_ * 4);

    if (ws_size >= need) {
        // ================= fast MFMA path =================
        split_key_kernel<<<dim3((B_ * S_ * D_) / 1024), 256, 0, stream>>>(key, kh, km, kl);
        split_mem_kernel<<<dim3((S_ * K_ * D_) / 1024), 256, 0, stream>>>(memory, mh, mm, ml);
        rownorm_kernel<<<dim3(S_ * K_), 64, 0, stream>>>(memory, invn);

        gemm_argmax_kernel<<<dim3(3584), 256, 0, stream>>>(
            kh, km, kl, mh, mm, ml, invn, pV, pI);
        combine1_kernel<<<dim3((S_ * B_) / 256), 256, 0, stream>>>(pV, pI, ind1);

        u1_hist_kernel<<<dim3(32, S_), 256, 0, stream>>>(ind1, hist);
        u2_scan_kernel<<<dim3(S_), 512, 0, stream>>>(hist, cnt, offs);
        u3_scatter_kernel<<<dim3(32, S_), 256, 0, stream>>>(ind1, hist, offs, csr);
        u4_gather_kernel<<<dim3(K_, S_), 64, 0, stream>>>(csr, cnt, offs, value, memory, newmem);

        rownorm_kernel<<<dim3(S_ * K_), 64, 0, stream>>>(newmem, invn);
        split_mem_kernel<<<dim3((S_ * K_ * D_) / 1024), 256, 0, stream>>>(newmem, mh, mm, ml);

        gemm_argmax_kernel<<<dim3(3584), 256, 0, stream>>>(
            kh, km, kl, mh, mm, ml, invn, pV, pI);
        combine2_out_kernel<<<dim3((S_ * B_) / 4), 256, 0, stream>>>(
            pV, pI, value, newmem, out);
    } else {
        // ================= fallback fp32 path (round-1, verified) =================
        float* invn1 = (float*)d_ws;
        float* invn2 = invn1 + S_ * K_;
        int*   find1 = (int*)(invn2 + S_ * K_);

        rownorm_kernel<<<dim3(S_ * K_), 64, 0, stream>>>(memory, invn1);
        score_argmax_kernel<0><<<dim3(B_ / 64, S_), 256, 0, stream>>>(
            key, memory, invn1, nullptr, nullptr, find1);
        update_kernel<<<dim3(K_ / 4, S_), 256, 0, stream>>>(find1, value, memory, newmem);
        rownorm_kernel<<<dim3(S_ * K_), 64, 0, stream>>>(newmem, invn2);
        score_argmax_kernel<1><<<dim3(B_ / 64, S_), 256, 0, stream>>>(
            key, newmem, invn2, value, out, nullptr);
    }
}

// Round 4
// 459.280 us; speedup vs baseline: 1.6465x; 1.6465x over previous
//
#include <hip/hip_runtime.h>
#include <cstddef>
#include <cstdint>

#define B_ 8192
#define S_ 14
#define K_ 512
#define D_ 256

typedef __attribute__((ext_vector_type(8))) short bfx8;
typedef __attribute__((ext_vector_type(4))) float fx4;

typedef __attribute__((address_space(3))) unsigned int       lds_u32;
typedef const __attribute__((address_space(1))) unsigned int glb_u32;

__device__ __forceinline__ void gload16(const void* g, void* l) {
    __builtin_amdgcn_global_load_lds((glb_u32*)g, (lds_u32*)l, 16, 0, 0);
}

// RNE float -> bf16 bits
__device__ __forceinline__ unsigned short f2bf(float x) {
    union { float f; unsigned int u; } v; v.f = x;
    unsigned int r = (v.u + 0x7FFFu + ((v.u >> 16) & 1u)) >> 16;
    return (unsigned short)r;
}
__device__ __forceinline__ float bf2f(unsigned short h) {
    union { unsigned int u; float f; } v; v.u = ((unsigned int)h) << 16;
    return v.f;
}

// ---------------------------------------------------------------------------
// per-row inverse L2 norm (1 wave per row of D=256 floats)  [fallback path]
// ---------------------------------------------------------------------------
__global__ __launch_bounds__(64) void rownorm_kernel(
    const float* __restrict__ rows, float* __restrict__ invn)
{
    const int row  = blockIdx.x;
    const int lane = threadIdx.x;
    const float4 v = *reinterpret_cast<const float4*>(rows + (size_t)row * D_ + lane * 4);
    float ss = v.x * v.x + v.y * v.y + v.z * v.z + v.w * v.w;
    #pragma unroll
    for (int m = 32; m >= 1; m >>= 1) ss += __shfl_xor(ss, m, 64);
    if (lane == 0) invn[row] = 1.0f / fmaxf(sqrtf(ss), 1e-12f);
}

// ---------------------------------------------------------------------------
// 3-way bf16 split of key (B,S,D) fp32 -> planes in (S,B,D) layout
// ---------------------------------------------------------------------------
__global__ __launch_bounds__(256) void split_key_kernel(
    const float* __restrict__ key,
    unsigned short* __restrict__ ph, unsigned short* __restrict__ pm,
    unsigned short* __restrict__ pl)
{
    const int gid  = blockIdx.x * 256 + threadIdx.x;
    const int e    = gid * 4;                 // flat elem in key natural order
    const int b    = e / (S_ * D_);
    const int rem  = e - b * (S_ * D_);
    const int s    = rem >> 8;                // D_=256
    const int d    = rem & 255;
    const float4 x = *reinterpret_cast<const float4*>(key + e);
    const size_t o = ((size_t)s * B_ + b) * D_ + d;

    float xs[4] = { x.x, x.y, x.z, x.w };
    unsigned short hh[4], mm[4], ll[4];
    #pragma unroll
    for (int i = 0; i < 4; ++i) {
        unsigned short a = f2bf(xs[i]);
        float r1 = xs[i] - bf2f(a);
        unsigned short bq = f2bf(r1);
        float r2 = r1 - bf2f(bq);
        unsigned short c = f2bf(r2);
        hh[i] = a; mm[i] = bq; ll[i] = c;
    }
    *reinterpret_cast<ushort4*>(ph + o) = make_ushort4(hh[0], hh[1], hh[2], hh[3]);
    *reinterpret_cast<ushort4*>(pm + o) = make_ushort4(mm[0], mm[1], mm[2], mm[3]);
    *reinterpret_cast<ushort4*>(pl + o) = make_ushort4(ll[0], ll[1], ll[2], ll[3]);
}

// ---------------------------------------------------------------------------
// fused: 3-way bf16 split of (S,K,D) rows + inverse L2 norm per row.
// One wave per row; identical split math to split_mem_kernel, identical
// norm math to rownorm_kernel -> bitwise-identical outputs, 2 launches -> 1.
// ---------------------------------------------------------------------------
__global__ __launch_bounds__(64) void splitnorm_mem_kernel(
    const float* __restrict__ mem,
    unsigned short* __restrict__ ph, unsigned short* __restrict__ pm,
    unsigned short* __restrict__ pl, float* __restrict__ invn)
{
    const int row  = blockIdx.x;          // s*K + k
    const int lane = threadIdx.x;
    const size_t e = (size_t)row * D_ + lane * 4;
    const float4 x = *reinterpret_cast<const float4*>(mem + e);

    float xs[4] = { x.x, x.y, x.z, x.w };
    unsigned short hh[4], mm[4], ll[4];
    #pragma unroll
    for (int i = 0; i < 4; ++i) {
        unsigned short a = f2bf(xs[i]);
        float r1 = xs[i] - bf2f(a);
        unsigned short bq = f2bf(r1);
        float r2 = r1 - bf2f(bq);
        unsigned short c = f2bf(r2);
        hh[i] = a; mm[i] = bq; ll[i] = c;
    }
    *reinterpret_cast<ushort4*>(ph + e) = make_ushort4(hh[0], hh[1], hh[2], hh[3]);
    *reinterpret_cast<ushort4*>(pm + e) = make_ushort4(mm[0], mm[1], mm[2], mm[3]);
    *reinterpret_cast<ushort4*>(pl + e) = make_ushort4(ll[0], ll[1], ll[2], ll[3]);

    float ss = x.x * x.x + x.y * x.y + x.z * x.z + x.w * x.w;
    #pragma unroll
    for (int m = 32; m >= 1; m >>= 1) ss += __shfl_xor(ss, m, 64);
    if (lane == 0) invn[row] = 1.0f / fmaxf(sqrtf(ss), 1e-12f);
}

// ---------------------------------------------------------------------------
// MFMA score GEMM + per-block argmax partials.
// Round-4 geometry: 512 thr = 8 waves (4m x 2n), block tile 256(b) x 128(k),
// wave tile 64x64 (acc 4x4, same inner structure as verified round-2).
// LDS = 3 A-planes 256x32 + 3 B-planes 128x32 = 72KB -> exactly 2 blocks/CU
// -> 16 waves/CU (4/SIMD) vs round-2's 10; staging bytes per FLOP -25%.
// Register budget at 4 waves/SIMD is 128/wave total: NO bf hoist (round-0
// read pattern, live set ~ acc64 + af16 + bf16 + addr ~ 110).
// __launch_bounds__(512,4) enforces the cap.  Spill signature to watch:
// WRITE_SIZE >> 4MB (round-3 failure) -> revert.
// Per-acc pair/dc accumulation order UNCHANGED -> scores bitwise identical.
// XOR-swizzled staging/reads (verified).  Bijective XCD swizzle, by fastest.
// Epilogue scratch (sInv/bV/bI) overlays the tile buffer after final barrier.
// ---------------------------------------------------------------------------
__global__ __launch_bounds__(512, 4) void gemm_argmax_kernel(
    const unsigned short* __restrict__ kh, const unsigned short* __restrict__ km,
    const unsigned short* __restrict__ kl,
    const unsigned short* __restrict__ mh, const unsigned short* __restrict__ mm_,
    const unsigned short* __restrict__ ml,
    const float* __restrict__ invn,
    float* __restrict__ pV, int* __restrict__ pI)
{
    // A planes at [p*8192] (256x32 each), B planes at [24576 + p*4096] (128x32)
    __shared__ __align__(16) short T[36864];   // 72 KiB

    // bijective XCD swizzle (nwg = 1792 = 8*224)
    const int orig = blockIdx.x;
    const int wg   = (orig & 7) * 224 + (orig >> 3);
    const int by   = wg & 3;          // k-block (fastest: key-tile sharers adjacent)
    const int bx   = (wg >> 2) & 31;  // b-block
    const int s    = wg >> 7;

    const int t    = threadIdx.x;
    const int b0   = bx * 256;
    const int n0   = by * 128;
    const int w    = t >> 6;          // 0..7
    const int lane = t & 63;
    const int wm   = w >> 1;          // 0..3  (64-row group)
    const int wn   = w & 1;           // 0..1  (64-col group)
    const int lr   = lane & 15, lg = lane >> 4;

    const size_t sB = (size_t)s * B_;
    const size_t sK = (size_t)s * K_;

    const unsigned short* __restrict__ APl[3] = { kh, km, kl };
    const unsigned short* __restrict__ BPl[3] = { mh, mm_, ml };

    fx4 acc[4][4];
    #pragma unroll
    for (int i = 0; i < 4; ++i)
        #pragma unroll
        for (int j = 0; j < 4; ++j) acc[i][j] = (fx4)0.0f;

    // staging: lane covers (row = l>>2, phys chunk = l&3);
    // pre-swizzled source chunk = (l&3) ^ ((l>>3)&3)
    const int rsub = lane >> 2;
    const int csw  = (((lane & 3) ^ ((lane >> 3) & 3)) * 8);
    // read-side: phys chunk = lg ^ ((row>>1)&3)
    const int rdof = ((lg ^ ((lr >> 1) & 3)) * 8);

    for (int dc = 0; dc < 8; ++dc) {
        // ---- stage 6 tiles (9 gload16/thread) ----
        const int dco = dc * 32 + csw;
        #pragma unroll
        for (int p = 0; p < 3; ++p) {
            #pragma unroll
            for (int u = 0; u < 2; ++u) {              // A: 256 rows, 32/wave
                const int R0 = w * 32 + u * 16;
                gload16(APl[p] + (sB + b0 + R0 + rsub) * D_ + dco,
                        &T[p * 8192 + R0 * 32]);
            }
            {                                          // B: 128 rows, 16/wave
                const int R0 = w * 16;
                gload16(BPl[p] + (sK + n0 + R0 + rsub) * D_ + dco,
                        &T[24576 + p * 4096 + R0 * 32]);
            }
        }
        __syncthreads();   // vmcnt(0) drain: all 6 tiles resident

        // ---- compute 6 term-pairs from LDS (pair order unchanged) ----
        #pragma unroll
        for (int ap = 0; ap < 3; ++ap) {
            bfx8 af[4];
            #pragma unroll
            for (int i = 0; i < 4; ++i)
                af[i] = *reinterpret_cast<const bfx8*>(
                    &T[ap * 8192 + (wm * 64 + i * 16 + lr) * 32 + rdof]);
            #pragma unroll
            for (int bp = 0; bp < 3 - ap; ++bp) {
                bfx8 bfr[4];
                #pragma unroll
                for (int j = 0; j < 4; ++j)
                    bfr[j] = *reinterpret_cast<const bfx8*>(
                        &T[24576 + bp * 4096 + (wn * 64 + j * 16 + lr) * 32 + rdof]);
                __builtin_amdgcn_s_setprio(1);
                #pragma unroll
                for (int i = 0; i < 4; ++i)
                    #pragma unroll
                    for (int j = 0; j < 4; ++j)
                        acc[i][j] = __builtin_amdgcn_mfma_f32_16x16x32_bf16(
                            af[i], bfr[j], acc[i][j], 0, 0, 0);
                __builtin_amdgcn_s_setprio(0);
            }
        }
        __syncthreads();   // everyone done reading before next stage overwrites
    }

    // ---- epilogue: overlay scratch on tile buffer (free after final barrier) ----
    float* sInv = reinterpret_cast<float*>(&T[0]);      // 128 f32
    float* bVp  = sInv + 128;                           // [256][2] f32
    int*   bIp  = reinterpret_cast<int*>(bVp + 512);    // [256][2] i32

    if (t < 128) sInv[t] = invn[sK + n0 + t];
    __syncthreads();

    #pragma unroll
    for (int i = 0; i < 4; ++i) {
        #pragma unroll
        for (int r = 0; r < 4; ++r) {
            float bv = -3.4e38f; int bi = 0x7fffffff;
            #pragma unroll
            for (int j = 0; j < 4; ++j) {
                const int kloc = wn * 64 + j * 16 + lr;
                const float v  = acc[i][j][r] * sInv[kloc];
                const int  kg  = n0 + kloc;
                if (v > bv || (v == bv && kg < bi)) { bv = v; bi = kg; }
            }
            #pragma unroll
            for (int msk = 1; msk < 16; msk <<= 1) {
                const float ov = __shfl_xor(bv, msk, 64);
                const int   oi = __shfl_xor(bi, msk, 64);
                if (ov > bv || (ov == bv && oi < bi)) { bv = ov; bi = oi; }
            }
            if (lr == 0) {
                const int mrow = wm * 64 + i * 16 + lg * 4 + r;
                bVp[mrow * 2 + wn] = bv; bIp[mrow * 2 + wn] = bi;
            }
        }
    }
    __syncthreads();

    if (t < 256) {   // 256 threads <-> 256 rows
        const float v0 = bVp[t * 2], v1 = bVp[t * 2 + 1];
        const int   i0 = bIp[t * 2], i1 = bIp[t * 2 + 1];
        const bool take1 = (v1 > v0) || (v1 == v0 && i1 < i0);
        const size_t o = ((size_t)s * 4 + by) * B_ + b0 + t;
        pV[o] = take1 ? v1 : v0;
        pI[o] = take1 ? i1 : i0;
    }
}

// ---------------------------------------------------------------------------
// combine 4 n-block partials -> ind1[s*B+b]
// ---------------------------------------------------------------------------
__global__ __launch_bounds__(256) void combine1_kernel(
    const float* __restrict__ pV, const int* __restrict__ pI,
    int* __restrict__ ind1)
{
    const int idx = blockIdx.x * 256 + threadIdx.x;   // s*B + b
    const int s   = idx >> 13;                        // B_=8192
    const int b   = idx & 8191;
    float bv = -3.4e38f; int bi = 0x7fffffff;
    #pragma unroll
    for (int nb = 0; nb < 4; ++nb) {
        const size_t o = ((size_t)s * 4 + nb) * B_ + b;
        const float v = pV[o]; const int i = pI[o];
        if (v > bv || (v == bv && i < bi)) { bv = v; bi = i; }
    }
    ind1[idx] = bi;
}

// ---------------------------------------------------------------------------
// combine partials -> ind2, gather output row
// ---------------------------------------------------------------------------
__global__ __launch_bounds__(256) void combine2_out_kernel(
    const float* __restrict__ pV, const int* __restrict__ pI,
    const float* __restrict__ value, const float* __restrict__ newmem,
    float* __restrict__ out)
{
    const int row  = blockIdx.x * 4 + (threadIdx.x >> 6);  // s*B + b
    const int lane = threadIdx.x & 63;
    const int s    = row >> 13;
    const int b    = row & 8191;
    float bv = -3.4e38f; int bi = 0x7fffffff;
    #pragma unroll
    for (int nb = 0; nb < 4; ++nb) {
        const size_t o = ((size_t)s * 4 + nb) * B_ + b;
        const float v = pV[o]; const int i = pI[o];
        if (v > bv || (v == bv && i < bi)) { bv = v; bi = i; }
    }
    const float4 vv = *reinterpret_cast<const float4*>(
        value + (size_t)b * (S_ * D_) + lane * 4);          // value[b][0][:]
    const float4 mmv = *reinterpret_cast<const float4*>(
        newmem + ((size_t)s * K_ + bi) * D_ + lane * 4);
    float4 o4;
    o4.x = vv.x + mmv.x; o4.y = vv.y + mmv.y;
    o4.z = vv.z + mmv.z; o4.w = vv.w + mmv.w;
    *reinterpret_cast<float4*>(out + ((size_t)b * S_ + s) * D_ + lane * 4) = o4;
}

// ---------------------------------------------------------------------------
// update chain: deterministic chunked counting sort + gather-EMA
// ---------------------------------------------------------------------------
__global__ __launch_bounds__(256) void u1_hist_kernel(
    const int* __restrict__ ind1, int* __restrict__ hist)
{
    __shared__ int h[K_];
    const int t = threadIdx.x, c = blockIdx.x, s = blockIdx.y;
    h[t] = 0; h[t + 256] = 0;
    __syncthreads();
    const int k = ind1[(size_t)s * B_ + c * 256 + t];
    atomicAdd(&h[k], 1);
    __syncthreads();
    hist[((size_t)s * 32 + c) * K_ + t]       = h[t];
    hist[((size_t)s * 32 + c) * K_ + t + 256] = h[t + 256];
}

__global__ __launch_bounds__(512) void u2_scan_kernel(
    int* __restrict__ hist, int* __restrict__ cnt, int* __restrict__ offs)
{
    __shared__ int sc[K_];
    const int k = threadIdx.x, s = blockIdx.x;
    int run = 0;
    for (int c = 0; c < 32; ++c) {
        const size_t o = ((size_t)s * 32 + c) * K_ + k;
        const int x = hist[o];
        hist[o] = run;           // exclusive per-chunk base within slot
        run += x;
    }
    cnt[s * K_ + k] = run;
    sc[k] = run;
    __syncthreads();
    for (int off = 1; off < K_; off <<= 1) {
        int v = (k >= off) ? sc[k - off] : 0;
        __syncthreads();
        sc[k] += v;
        __syncthreads();
    }
    offs[s * K_ + k] = sc[k] - run;   // exclusive slot base
}

__global__ __launch_bounds__(256) void u3_scatter_kernel(
    const int* __restrict__ ind1, const int* __restrict__ hist,
    const int* __restrict__ offs, int* __restrict__ csr)
{
    __shared__ int sk[256];
    const int t = threadIdx.x, c = blockIdx.x, s = blockIdx.y;
    const int b = c * 256 + t;
    const int k = ind1[(size_t)s * B_ + b];
    sk[t] = k;
    __syncthreads();
    int rank = 0;
    for (int j = 0; j < t; ++j) rank += (sk[j] == k);
    const int pos = offs[s * K_ + k] + hist[((size_t)s * 32 + c) * K_ + k] + rank;
    csr[(size_t)s * B_ + pos] = b;
}

__global__ __launch_bounds__(64) void u4_gather_kernel(
    const int* __restrict__ csr, const int* __restrict__ cnt,
    const int* __restrict__ offs, const float* __restrict__ value,
    const float* __restrict__ memory, float* __restrict__ newmem)
{
    const int k = blockIdx.x, s = blockIdx.y, lane = threadIdx.x;
    const int n = cnt[s * K_ + k];
    const int base = offs[s * K_ + k];
    float4 a; a.x = a.y = a.z = a.w = 0.0f;
    for (int i = 0; i < n; ++i) {
        const int b = csr[(size_t)s * B_ + base + i];
        const float4 v = *reinterpret_cast<const float4*>(
            value + ((size_t)b * S_ + s) * D_ + lane * 4);
        a.x += v.x; a.y += v.y; a.z += v.z; a.w += v.w;
    }
    const float inv = 1.0f / ((float)n + 1e-6f);
    const size_t o = ((size_t)s * K_ + k) * D_ + lane * 4;
    const float4 mo = *reinterpret_cast<const float4*>(memory + o);
    float4 r;
    r.x = mo.x * 0.999f + a.x * inv * 0.001f;
    r.y = mo.y * 0.999f + a.y * inv * 0.001f;
    r.z = mo.z * 0.999f + a.z * inv * 0.001f;
    r.w = mo.w * 0.999f + a.w * inv * 0.001f;
    *reinterpret_cast<float4*>(newmem + o) = r;
}

// ===========================================================================
// FALLBACK (round-1 verified fp32 path; used if ws too small)
// ===========================================================================
template <int MODE>
__global__ __launch_bounds__(256) void score_argmax_kernel(
    const float* __restrict__ key, const float* __restrict__ mem,
    const float* __restrict__ invn, const float* __restrict__ value,
    float* __restrict__ out, int* __restrict__ ind_out)
{
    __shared__ __align__(16) float kt[64][36];
    __shared__ __align__(16) float mt[64][36];
    __shared__ float redV[64][16];
    __shared__ int   redI[64][16];

    const int t  = threadIdx.x;
    const int s  = blockIdx.y;
    const int b0 = blockIdx.x * 64;
    const int tb = t & 15;
    const int tk = t >> 4;

    float best[4]; int bidx[4];
    #pragma unroll
    for (int i = 0; i < 4; ++i) { best[i] = -3.4e38f; bidx[i] = 0; }

    for (int kc = 0; kc < 8; ++kc) {
        float acc[4][4];
        #pragma unroll
        for (int i = 0; i < 4; ++i)
            #pragma unroll
            for (int j = 0; j < 4; ++j) acc[i][j] = 0.0f;

        for (int dc = 0; dc < 8; ++dc) {
            #pragma unroll
            for (int u = 0; u < 2; ++u) {
                const int f = t + u * 256;
                const int row = f >> 3;
                const int c4 = f & 7;
                *reinterpret_cast<float4*>(&kt[row][c4 * 4]) =
                    *reinterpret_cast<const float4*>(
                        key + (((size_t)(b0 + row)) * S_ + s) * D_ + dc * 32 + c4 * 4);
                *reinterpret_cast<float4*>(&mt[row][c4 * 4]) =
                    *reinterpret_cast<const float4*>(
                        mem + (((size_t)s * K_) + kc * 64 + row) * D_ + dc * 32 + c4 * 4);
            }
            __syncthreads();
            #pragma unroll
            for (int d4 = 0; d4 < 8; ++d4) {
                float4 a[4], b[4];
                #pragma unroll
                for (int i = 0; i < 4; ++i)
                    a[i] = *reinterpret_cast<const float4*>(&kt[tb + i * 16][d4 * 4]);
                #pragma unroll
                for (int j = 0; j < 4; ++j)
                    b[j] = *reinterpret_cast<const float4*>(&mt[tk + j * 16][d4 * 4]);
                #pragma unroll
                for (int i = 0; i < 4; ++i)
                    #pragma unroll
                    for (int j = 0; j < 4; ++j)
                        acc[i][j] += a[i].x * b[j].x + a[i].y * b[j].y +
                                     a[i].z * b[j].z + a[i].w * b[j].w;
            }
            __syncthreads();
        }
        #pragma unroll
        for (int j = 0; j < 4; ++j) {
            const int kabs = kc * 64 + tk + j * 16;
            const float inv = invn[s * K_ + kabs];
            #pragma unroll
            for (int i = 0; i < 4; ++i) {
                const float v = acc[i][j] * inv;
                if (v > best[i] || (v == best[i] && kabs < bidx[i])) {
                    best[i] = v; bidx[i] = kabs;
                }
            }
        }
    }
    #pragma unroll
    for (int i = 0; i < 4; ++i) {
        redV[tb + i * 16][tk] = best[i];
        redI[tb + i * 16][tk] = bidx[i];
    }
    __syncthreads();
    if (t < 64) {
        float bv = redV[t][0]; int bi = redI[t][0];
        #pragma unroll
        for (int g = 1; g < 16; ++g) {
            const float v = redV[t][g]; const int ix = redI[t][g];
            if (v > bv || (v == bv && ix < bi)) { bv = v; bi = ix; }
        }
        if (MODE == 0) ind_out[(size_t)s * B_ + b0 + t] = bi;
        else           redI[t][0] = bi;
    }
    if (MODE == 1) {
        __syncthreads();
        const int w = t >> 6, lane = t & 63;
        for (int r = w; r < 64; r += 4) {
            const int bg = b0 + r;
            const int kk = redI[r][0];
            const float4 vv = *reinterpret_cast<const float4*>(
                value + (size_t)bg * (S_ * D_) + lane * 4);
            const float4 mmv = *reinterpret_cast<const float4*>(
                mem + ((size_t)s * K_ + kk) * D_ + lane * 4);
            float4 o;
            o.x = vv.x + mmv.x; o.y = vv.y + mmv.y;
            o.z = vv.z + mmv.z; o.w = vv.w + mmv.w;
            *reinterpret_cast<float4*>(
                out + (((size_t)bg) * S_ + s) * D_ + lane * 4) = o;
        }
    }
}

__global__ __launch_bounds__(256) void update_kernel(
    const int* __restrict__ ind1, const float* __restrict__ value,
    const float* __restrict__ memory, float* __restrict__ newmem)
{
    const int k0 = blockIdx.x * 4, s = blockIdx.y, t = threadIdx.x;
    __shared__ int sIdx[256];
    float a0 = 0.f, a1 = 0.f, a2 = 0.f, a3 = 0.f;
    int c0 = 0, c1 = 0, c2 = 0, c3 = 0;
    for (int b0 = 0; b0 < B_; b0 += 256) {
        sIdx[t] = ind1[(size_t)s * B_ + b0 + t];
        __syncthreads();
        for (int bb = 0; bb < 256; ++bb) {
            const int ix = sIdx[bb];
            const unsigned r = (unsigned)(ix - k0);
            if (r < 4u) {
                const float v = value[(((size_t)(b0 + bb)) * S_ + s) * D_ + t];
                if      (r == 0u) { a0 += v; ++c0; }
                else if (r == 1u) { a1 += v; ++c1; }
                else if (r == 2u) { a2 += v; ++c2; }
                else              { a3 += v; ++c3; }
            }
        }
        __syncthreads();
    }
    const float accs[4] = { a0, a1, a2, a3 };
    const int   cns [4] = { c0, c1, c2, c3 };
    #pragma unroll
    for (int kk = 0; kk < 4; ++kk) {
        const size_t off = ((size_t)s * K_ + k0 + kk) * D_ + t;
        const float mean = accs[kk] / ((float)cns[kk] + 1e-6f);
        newmem[off] = memory[off] * 0.999f + mean * 0.001f;
    }
}

// ---------------------------------------------------------------------------
extern "C" void kernel_launch(void* const* d_in, const int* in_sizes, int n_in,
                              void* d_out, int out_size, void* d_ws, size_t ws_size,
                              hipStream_t stream)
{
    const float* key    = (const float*)d_in[0];
    const float* value  = (const float*)d_in[1];
    const float* memory = (const float*)d_in[2];

    float* out    = (float*)d_out;                       // (B,S,D)
    float* newmem = out + (size_t)B_ * S_ * D_;          // (S,K,D)

    // ---- workspace layout for the MFMA path ----
    const size_t keyPlane = (size_t)S_ * B_ * D_;        // elems (bf16)
    const size_t memPlane = (size_t)S_ * K_ * D_;
    char* p = (char*)d_ws;
    size_t need = 0;
    auto alloc = [&](size_t bytes) -> char* {
        char* r = p + need;
        need += (bytes + 255) & ~(size_t)255;
        return r;
    };
    unsigned short* kh  = (unsigned short*)alloc(keyPlane * 2);
    unsigned short* km  = (unsigned short*)alloc(keyPlane * 2);
    unsigned short* kl  = (unsigned short*)alloc(keyPlane * 2);
    unsigned short* mh  = (unsigned short*)alloc(memPlane * 2);
    unsigned short* mm  = (unsigned short*)alloc(memPlane * 2);
    unsigned short* ml  = (unsigned short*)alloc(memPlane * 2);
    float* invn   = (float*)alloc((size_t)S_ * K_ * 4);
    float* pV     = (float*)alloc((size_t)S_ * 4 * B_ * 4);
    int*   pI     = (int*)  alloc((size_t)S_ * 4 * B_ * 4);
    int*   ind1   = (int*)  alloc((size_t)S_ * B_ * 4);
    int*   hist   = (int*)  alloc((size_t)S_ * 32 * K_ * 4);
    int*   cnt    = (int*)  alloc((size_t)S_ * K_ * 4);
    int*   offs   = (int*)  alloc((size_t)S_ * K_ * 4);
    int*   csr    = (int*)  alloc((size_t)S_ * B_ * 4);

    if (ws_size >= need) {
        // ================= fast MFMA path =================
        split_key_kernel<<<dim3((B_ * S_ * D_) / 1024), 256, 0, stream>>>(key, kh, km, kl);
        splitnorm_mem_kernel<<<dim3(S_ * K_), 64, 0, stream>>>(memory, mh, mm, ml, invn);

        gemm_argmax_kernel<<<dim3(1792), 512, 0, stream>>>(
            kh, km, kl, mh, mm, ml, invn, pV, pI);
        combine1_kernel<<<dim3((S_ * B_) / 256), 256, 0, stream>>>(pV, pI, ind1);

        u1_hist_kernel<<<dim3(32, S_), 256, 0, stream>>>(ind1, hist);
        u2_scan_kernel<<<dim3(S_), 512, 0, stream>>>(hist, cnt, offs);
        u3_scatter_kernel<<<dim3(32, S_), 256, 0, stream>>>(ind1, hist, offs, csr);
        u4_gather_kernel<<<dim3(K_, S_), 64, 0, stream>>>(csr, cnt, offs, value, memory, newmem);

        splitnorm_mem_kernel<<<dim3(S_ * K_), 64, 0, stream>>>(newmem, mh, mm, ml, invn);

        gemm_argmax_kernel<<<dim3(1792), 512, 0, stream>>>(
            kh, km, kl, mh, mm, ml, invn, pV, pI);
        combine2_out_kernel<<<dim3((S_ * B_) / 4), 256, 0, stream>>>(
            pV, pI, value, newmem, out);
    } else {
        // ================= fallback fp32 path (round-1, verified) =================
        float* invn1 = (float*)d_ws;
        float* invn2 = invn1 + S_ * K_;
        int*   find1 = (int*)(invn2 + S_ * K_);

        rownorm_kernel<<<dim3(S_ * K_), 64, 0, stream>>>(memory, invn1);
        score_argmax_kernel<0><<<dim3(B_ / 64, S_), 256, 0, stream>>>(
            key, memory, invn1, nullptr, nullptr, find1);
        update_kernel<<<dim3(K_ / 4, S_), 256, 0, stream>>>(find1, value, memory, newmem);
        rownorm_kernel<<<dim3(S_ * K_), 64, 0, stream>>>(newmem, invn2);
        score_argmax_kernel<1><<<dim3(B_ / 64, S_), 256, 0, stream>>>(
            key, newmem, invn2, value, out, nullptr);
    }
}